// Round 9
// baseline (435.160 us; speedup 1.0000x reference)
//
#include <hip/hip_runtime.h>

#define N_NODES 50000
#define N_EDGES 800000
#define HID 128
#define OUTC 10
#define N_GRAPHS 64
#define BN_EPS 1e-5f

#define MLP_BLOCKS (N_NODES / 16)   // 3125, exact

// radix partition params
#define NB 196          // ceil(50000/256) buckets of 256 nodes
#define BCAP 5632       // per-bucket capacity (mean 4082, sigma~64; huge margin)
#define EPB 2048        // edges per phase-A block
#define NBLK_A ((N_EDGES + EPB - 1) / EPB)   // 391

typedef __attribute__((ext_vector_type(8))) short short8_t;
typedef __attribute__((ext_vector_type(4))) float f32x4;

__device__ __forceinline__ unsigned short f2bf(float f) {
    unsigned u = __float_as_uint(f);
    u += 0x7FFFu + ((u >> 16) & 1u);     // RNE
    return (unsigned short)(u >> 16);
}
__device__ __forceinline__ float bf2f(unsigned short s) {
    return __uint_as_float(((unsigned)s) << 16);
}
__device__ __forceinline__ float2 bfp2f(unsigned v) {
    float2 r;
    r.x = __uint_as_float(v << 16);
    r.y = __uint_as_float(v & 0xFFFF0000u);
    return r;
}

// ---------------- Phase A: bin edges into 196 coarse buckets ----------------
// ebuf entry: (dstLow8 << 16) | src16
__global__ __launch_bounds__(256) void k_bucket(const int* __restrict__ src,
                                                const int* __restrict__ dst,
                                                int* __restrict__ bucketCnt,
                                                unsigned* __restrict__ ebuf) {
    __shared__ int cnt[NB];
    __shared__ int base[NB];
    int t = threadIdx.x;
    for (int i = t; i < NB; i += 256) cnt[i] = 0;
    __syncthreads();
    int e0 = blockIdx.x * EPB;
    int e1 = e0 + EPB; if (e1 > N_EDGES) e1 = N_EDGES;
    for (int e = e0 + t; e < e1; e += 256)
        atomicAdd(&cnt[dst[e] >> 8], 1);
    __syncthreads();
    for (int i = t; i < NB; i += 256) {
        int c = cnt[i];
        base[i] = c ? atomicAdd(&bucketCnt[i], c) : 0;
        cnt[i] = 0;
    }
    __syncthreads();
    for (int e = e0 + t; e < e1; e += 256) {
        int d = dst[e];
        int s = src[e];
        int b = d >> 8;
        int r = atomicAdd(&cnt[b], 1);
        ebuf[(size_t)b * BCAP + base[b] + r] = ((unsigned)(d & 255) << 16) | (unsigned)s;
    }
}

// ---------------- Phase B: per-bucket local sort -> srcSorted + estart/eend ----------------
__global__ __launch_bounds__(256) void k_bsort(const int* __restrict__ bucketCnt,
                                               const unsigned* __restrict__ ebuf,
                                               unsigned short* __restrict__ srcSorted,
                                               int* __restrict__ estart,
                                               int* __restrict__ eend) {
    __shared__ int cnt[256];
    __shared__ int sh[256];
    __shared__ int pos[256];
    int b = blockIdx.x;
    int t = threadIdx.x;
    int n = bucketCnt[b];
    int bBase = b * BCAP;
    const unsigned* eb = ebuf + (size_t)bBase;
    cnt[t] = 0;
    __syncthreads();
    for (int i = t; i < n; i += 256) atomicAdd(&cnt[eb[i] >> 16], 1);
    __syncthreads();
    int v = cnt[t];
    sh[t] = v;
    __syncthreads();
    for (int off = 1; off < 256; off <<= 1) {
        int x = sh[t];
        if (t >= off) x += sh[t - off];
        __syncthreads();
        sh[t] = x;
        __syncthreads();
    }
    int excl = sh[t] - v;
    pos[t] = excl;
    int node = b * 256 + t;
    if (node < N_NODES) {
        estart[node] = bBase + excl;
        eend[node] = bBase + excl + v;
    }
    __syncthreads();
    for (int i = t; i < n; i += 256) {
        unsigned pe = eb[i];
        int dl = pe >> 16;
        int p = atomicAdd(&pos[dl], 1);
        srcSorted[bBase + p] = (unsigned short)(pe & 0xFFFFu);
    }
}

// ---------------- prep: x->bf16 cast + weight pre-pack + zero done-counters ----------------
#define X2BF_ITEMS (N_NODES * HID / 8)   // 800000
__global__ void k_prep(const float* __restrict__ x, const float* __restrict__ W1s,
                       const float* __restrict__ W2s,
                       unsigned short* __restrict__ xbf, unsigned short* __restrict__ Wp,
                       int* __restrict__ doneBN, int* __restrict__ donePool) {
    int gid = blockIdx.x * 256 + threadIdx.x;
    if (gid == 0) { *doneBN = 0; *donePool = 0; }
    if (gid < X2BF_ITEMS) {
        const float4* p = (const float4*)&x[(size_t)gid * 8];
        float4 a = p[0], b = p[1];
        short8_t o = { (short)f2bf(a.x), (short)f2bf(a.y), (short)f2bf(a.z), (short)f2bf(a.w),
                       (short)f2bf(b.x), (short)f2bf(b.y), (short)f2bf(b.z), (short)f2bf(b.w) };
        *(short8_t*)&xbf[(size_t)gid * 8] = o;
    } else {
        int idx = gid - X2BF_ITEMS;
        if (idx >= 6 * 2048) return;
        int mat = idx >> 11;
        int rem = idx & 2047;
        int lane = rem & 63;
        int ks = (rem >> 6) & 3;
        int nt = rem >> 8;
        int l = mat >> 1;
        const float* W = (mat & 1) ? (W2s + (size_t)l * HID * HID) : (W1s + (size_t)l * HID * HID);
        int n = nt * 16 + (lane & 15);
        int k0 = ks * 32 + (lane >> 4) * 8;
        short8_t o;
#pragma unroll
        for (int j = 0; j < 8; j++) o[j] = (short)f2bf(W[(size_t)(k0 + j) * HID + n]);
        *(short8_t*)&Wp[(size_t)idx * 8] = o;
    }
}

// ---------------- Fused aggregation + MFMA MLP (unchanged structure from R8) ----------------
#define MPITCH 136

template <bool BN>
__global__ __launch_bounds__(256) void k_aggmlp(const unsigned short* __restrict__ X,
                                                const float* __restrict__ sc,
                                                const int* __restrict__ estart,
                                                const int* __restrict__ eend,
                                                const unsigned short* __restrict__ srcSorted,
                                                const unsigned short* __restrict__ W1p,
                                                const float* __restrict__ b1,
                                                const unsigned short* __restrict__ W2p,
                                                const float* __restrict__ b2,
                                                unsigned short* __restrict__ hbf,
                                                float* __restrict__ bnpart) {
    __shared__ __align__(16) unsigned short As[16 * MPITCH];
    __shared__ __align__(16) unsigned short Ts[16 * MPITCH];

    int tid = threadIdx.x;
    int wave = tid >> 6;
    int lane = tid & 63;
    int lrow = lane & 15;
    int quad = lane >> 4;
    int half = lane >> 5;
    int hl = lane & 31;
    int hq = hl >> 4;
    int rowBase = blockIdx.x * 16;
    int col0 = lrow * 8;

    float scv[8], shv[8];
    if (BN) {
#pragma unroll
        for (int j = 0; j < 8; j++) { scv[j] = sc[col0 + j]; shv[j] = sc[HID + col0 + j]; }
    }

    for (int pr = 0; pr < 2; pr++) {
        int tr = wave * 4 + pr * 2 + half;
        int node = rowBase + tr;
        float acc[8];
        {
            short8_t ov = *(const short8_t*)&X[(size_t)node * HID + col0];
            uint4 uu = *(uint4*)&ov;
            float2 p0 = bfp2f(uu.x), p1 = bfp2f(uu.y), p2 = bfp2f(uu.z), p3 = bfp2f(uu.w);
            float f[8] = { p0.x, p0.y, p1.x, p1.y, p2.x, p2.y, p3.x, p3.y };
#pragma unroll
            for (int j = 0; j < 8; j++) {
                float v = BN ? fmaxf(f[j] * scv[j] + shv[j], 0.f) : f[j];
                acc[j] = (hq == 0) ? v : 0.f;
            }
        }

        int e0 = estart[node];
        int deg = eend[node] - e0;

        for (int base = 0; base < deg; base += 16) {
            int cnt = deg - base; if (cnt > 16) cnt = 16;
            int ipos = base + (hl & 15); if (ipos >= deg) ipos = deg - 1;
            int myidx = (int)srcSorted[e0 + ipos];

            short8_t v[8];
#pragma unroll
            for (int u = 0; u < 8; u++) {
                int slot = u * 2 + hq;
                int sl = slot < cnt ? slot : cnt - 1;
                int ridx = __shfl(myidx, (half << 5) + sl);
                v[u] = *(const short8_t*)&X[(size_t)ridx * HID + col0];
            }
#pragma unroll
            for (int u = 0; u < 8; u++) {
                int slot = u * 2 + hq;
                if (slot < cnt) {
                    uint4 uu = *(uint4*)&v[u];
                    float2 p0 = bfp2f(uu.x), p1 = bfp2f(uu.y), p2 = bfp2f(uu.z), p3 = bfp2f(uu.w);
                    float f[8] = { p0.x, p0.y, p1.x, p1.y, p2.x, p2.y, p3.x, p3.y };
#pragma unroll
                    for (int j = 0; j < 8; j++)
                        acc[j] += BN ? fmaxf(f[j] * scv[j] + shv[j], 0.f) : f[j];
                }
            }
        }

#pragma unroll
        for (int j = 0; j < 8; j++) acc[j] += __shfl_xor(acc[j], 16);
        if (hq == 0) {
            short8_t o;
#pragma unroll
            for (int j = 0; j < 8; j++) o[j] = (short)f2bf(acc[j]);
            *(short8_t*)&As[tr * MPITCH + col0] = o;
        }
    }
    __syncthreads();

    int t0 = wave * 2;
    short8_t a0f = *(const short8_t*)&As[lrow * MPITCH + 0 * 32 + quad * 8];
    short8_t a1f = *(const short8_t*)&As[lrow * MPITCH + 1 * 32 + quad * 8];
    short8_t a2f = *(const short8_t*)&As[lrow * MPITCH + 2 * 32 + quad * 8];
    short8_t a3f = *(const short8_t*)&As[lrow * MPITCH + 3 * 32 + quad * 8];

    f32x4 acc1[2];
#pragma unroll
    for (int ti = 0; ti < 2; ti++) {
        int t = t0 + ti;
        f32x4 a = (f32x4){ 0.f, 0.f, 0.f, 0.f };
        short8_t b0 = *(const short8_t*)&W1p[(size_t)((t * 4 + 0) * 64 + lane) * 8];
        short8_t b1_ = *(const short8_t*)&W1p[(size_t)((t * 4 + 1) * 64 + lane) * 8];
        short8_t b2_ = *(const short8_t*)&W1p[(size_t)((t * 4 + 2) * 64 + lane) * 8];
        short8_t b3 = *(const short8_t*)&W1p[(size_t)((t * 4 + 3) * 64 + lane) * 8];
        a = __builtin_amdgcn_mfma_f32_16x16x32_bf16(a0f, b0, a, 0, 0, 0);
        a = __builtin_amdgcn_mfma_f32_16x16x32_bf16(a1f, b1_, a, 0, 0, 0);
        a = __builtin_amdgcn_mfma_f32_16x16x32_bf16(a2f, b2_, a, 0, 0, 0);
        a = __builtin_amdgcn_mfma_f32_16x16x32_bf16(a3f, b3, a, 0, 0, 0);
        acc1[ti] = a;
    }

#pragma unroll
    for (int ti = 0; ti < 2; ti++) {
        int col = (t0 + ti) * 16 + lrow;
        float bb = b1[col];
#pragma unroll
        for (int r = 0; r < 4; r++) {
            float v = fmaxf(acc1[ti][r] + bb, 0.f);
            Ts[(quad * 4 + r) * MPITCH + col] = f2bf(v);
        }
    }
    __syncthreads();

    short8_t t0f = *(const short8_t*)&Ts[lrow * MPITCH + 0 * 32 + quad * 8];
    short8_t t1f = *(const short8_t*)&Ts[lrow * MPITCH + 1 * 32 + quad * 8];
    short8_t t2f = *(const short8_t*)&Ts[lrow * MPITCH + 2 * 32 + quad * 8];
    short8_t t3f = *(const short8_t*)&Ts[lrow * MPITCH + 3 * 32 + quad * 8];

    f32x4 acc2[2];
#pragma unroll
    for (int ti = 0; ti < 2; ti++) {
        int t = t0 + ti;
        f32x4 a = (f32x4){ 0.f, 0.f, 0.f, 0.f };
        short8_t b0 = *(const short8_t*)&W2p[(size_t)((t * 4 + 0) * 64 + lane) * 8];
        short8_t b1_ = *(const short8_t*)&W2p[(size_t)((t * 4 + 1) * 64 + lane) * 8];
        short8_t b2_ = *(const short8_t*)&W2p[(size_t)((t * 4 + 2) * 64 + lane) * 8];
        short8_t b3 = *(const short8_t*)&W2p[(size_t)((t * 4 + 3) * 64 + lane) * 8];
        a = __builtin_amdgcn_mfma_f32_16x16x32_bf16(t0f, b0, a, 0, 0, 0);
        a = __builtin_amdgcn_mfma_f32_16x16x32_bf16(t1f, b1_, a, 0, 0, 0);
        a = __builtin_amdgcn_mfma_f32_16x16x32_bf16(t2f, b2_, a, 0, 0, 0);
        a = __builtin_amdgcn_mfma_f32_16x16x32_bf16(t3f, b3, a, 0, 0, 0);
        acc2[ti] = a;
    }

#pragma unroll
    for (int ti = 0; ti < 2; ti++) {
        int t = t0 + ti;
        int col = t * 16 + lrow;
        float bb = b2[col];
        float p1 = 0.f, p2 = 0.f;
#pragma unroll
        for (int r = 0; r < 4; r++) {
            unsigned short bv = f2bf(acc2[ti][r] + bb);
            float vr = bf2f(bv);
            p1 += vr; p2 += vr * vr;
            As[(quad * 4 + r) * MPITCH + col] = bv;
        }
        p1 += __shfl_xor(p1, 16); p1 += __shfl_xor(p1, 32);
        p2 += __shfl_xor(p2, 16); p2 += __shfl_xor(p2, 32);
        if (quad == 0) {
            float* bp = bnpart + (size_t)blockIdx.x * 256;
            bp[t * 16 + lrow] = p1;
            bp[128 + t * 16 + lrow] = p2;
        }
    }
    __syncthreads();

    {
        int r = tid >> 4;
        int c8 = (tid & 15) * 8;
        *(short8_t*)&hbf[(size_t)(rowBase + r) * HID + c8] =
            *(const short8_t*)&As[r * MPITCH + c8];
    }
}

// ---------------- BN reduce + scale/shift, fused (last-block-done) ----------------
__global__ void k_bnfin(const float* __restrict__ bnpart, const float* __restrict__ gamma,
                        const float* __restrict__ beta, float* __restrict__ bnred2,
                        float* __restrict__ sc, int* __restrict__ done) {
    int t = threadIdx.x;
    float acc = 0.f;
    for (int r = blockIdx.x; r < MLP_BLOCKS; r += 64)
        acc += bnpart[(size_t)r * 256 + t];
    bnred2[blockIdx.x * 256 + t] = acc;
    __threadfence();
    __shared__ int lastFlag;
    if (t == 0) lastFlag = (atomicAdd(done, 1) == 63);
    __syncthreads();
    if (lastFlag) {
        __shared__ float tot[256];
        volatile const float* br = bnred2;
        float a = 0.f;
        for (int j = 0; j < 64; j++) a += br[j * 256 + t];
        tot[t] = a;
        __syncthreads();
        if (t < HID) {
            float mean = tot[t] * (1.0f / N_NODES);
            float var = tot[HID + t] * (1.0f / N_NODES) - mean * mean;
            float s = gamma[t] * rsqrtf(var + BN_EPS);
            sc[t] = s;
            sc[HID + t] = beta[t] - mean * s;
        }
        if (t == 0) *done = 0;   // reset for next layer
    }
}

// ---------------- Pool (BN+ReLU fused) + final linear (last-block-done) ----------------
#define POOL_CHUNK 512
#define POOL_BLOCKS ((N_NODES + POOL_CHUNK - 1) / POOL_CHUNK)   // 98
__global__ void k_poolfin(const unsigned short* __restrict__ X, const float* __restrict__ sc,
                          const int* __restrict__ batch, float* __restrict__ g,
                          const float* __restrict__ Wlin, const float* __restrict__ blin,
                          float* __restrict__ out, int* __restrict__ done) {
    int lane = threadIdx.x & 31;
    int rg = threadIdx.x >> 5;
    int c = lane * 4;
    float4 s = *(const float4*)&sc[c];
    float4 b = *(const float4*)&sc[HID + c];
    int base = blockIdx.x * POOL_CHUNK;
    int end = base + POOL_CHUNK;
    if (end > N_NODES) end = N_NODES;
    float a0 = 0.f, a1 = 0.f, a2 = 0.f, a3 = 0.f;
    int cur = -1;
    for (int r = base + rg; r < end; r += 8) {
        int bb = batch[r];
        if (bb != cur) {
            if (cur >= 0) {
                atomicAdd(&g[cur * HID + c + 0], a0);
                atomicAdd(&g[cur * HID + c + 1], a1);
                atomicAdd(&g[cur * HID + c + 2], a2);
                atomicAdd(&g[cur * HID + c + 3], a3);
            }
            cur = bb;
            a0 = a1 = a2 = a3 = 0.f;
        }
        ushort4 v = *(const ushort4*)&X[(size_t)r * HID + c];
        a0 += fmaxf(bf2f(v.x) * s.x + b.x, 0.f);
        a1 += fmaxf(bf2f(v.y) * s.y + b.y, 0.f);
        a2 += fmaxf(bf2f(v.z) * s.z + b.z, 0.f);
        a3 += fmaxf(bf2f(v.w) * s.w + b.w, 0.f);
    }
    if (cur >= 0) {
        atomicAdd(&g[cur * HID + c + 0], a0);
        atomicAdd(&g[cur * HID + c + 1], a1);
        atomicAdd(&g[cur * HID + c + 2], a2);
        atomicAdd(&g[cur * HID + c + 3], a3);
    }
    __threadfence();
    __shared__ int lastFlag;
    if (threadIdx.x == 0) lastFlag = (atomicAdd(done, 1) == POOL_BLOCKS - 1);
    __syncthreads();
    if (lastFlag) {
        volatile const float* gv = g;
        for (int o = threadIdx.x; o < N_GRAPHS * OUTC; o += 256) {
            int gi = o / OUTC, cc = o % OUTC;
            float acc = blin[cc];
            for (int k = 0; k < HID; k++) acc += gv[gi * HID + k] * Wlin[k * OUTC + cc];
            out[o] = acc;
        }
    }
}

// ---------------- Launch ----------------
extern "C" void kernel_launch(void* const* d_in, const int* in_sizes, int n_in,
                              void* d_out, int out_size, void* d_ws, size_t ws_size,
                              hipStream_t stream) {
    const float* x      = (const float*)d_in[0];
    const float* W1s    = (const float*)d_in[1];
    const float* b1s    = (const float*)d_in[2];
    const float* W2s    = (const float*)d_in[3];
    const float* b2s    = (const float*)d_in[4];
    const float* gammas = (const float*)d_in[5];
    const float* betas  = (const float*)d_in[6];
    const float* Wlin   = (const float*)d_in[7];
    const float* blin   = (const float*)d_in[8];
    const int* edge_index = (const int*)d_in[9];
    const int* batch    = (const int*)d_in[10];
    float* out = (float*)d_out;

    const int* src = edge_index;
    const int* dst = edge_index + N_EDGES;

    char* w = (char*)d_ws;
    int* bucketCnt = (int*)w;        w += 256 * 4;
    int* doneBN    = (int*)w;        w += 64;
    int* donePool  = (int*)w;        w += 64;
    unsigned* ebuf = (unsigned*)w;   w += (size_t)NB * BCAP * 4;         // 4.4 MB
    unsigned short* srcSorted = (unsigned short*)w; w += (size_t)NB * BCAP * 2; // 2.2 MB
    int* estart    = (int*)w;        w += (size_t)N_NODES * 4;
    int* eend      = (int*)w;        w += (size_t)N_NODES * 4;
    unsigned short* Xbf = (unsigned short*)w; w += (size_t)N_NODES * HID * 2;   // 12.8 MB
    unsigned short* HA  = (unsigned short*)w; w += (size_t)N_NODES * HID * 2;
    unsigned short* HB  = (unsigned short*)w; w += (size_t)N_NODES * HID * 2;
    unsigned short* Wp  = (unsigned short*)w; w += (size_t)6 * 2048 * 8 * 2;
    float* bnpart = (float*)w; w += (size_t)MLP_BLOCKS * 256 * 4;        // 3.2 MB
    float* bnred2 = (float*)w; w += (size_t)64 * 256 * 4;
    float* bnsc   = (float*)w; w += 2 * HID * 4;
    float* g      = (float*)w; w += (size_t)N_GRAPHS * HID * 4;

    hipMemsetAsync(bucketCnt, 0, 256 * 4, stream);
    hipMemsetAsync(g, 0, (size_t)N_GRAPHS * HID * 4, stream);

    k_bucket<<<NBLK_A, 256, 0, stream>>>(src, dst, bucketCnt, ebuf);
    k_bsort<<<NB, 256, 0, stream>>>(bucketCnt, ebuf, srcSorted, estart, eend);
    k_prep<<<(X2BF_ITEMS + 6 * 2048 + 255) / 256, 256, 0, stream>>>(
        x, W1s, W2s, Xbf, Wp, doneBN, donePool);

    // layer 0: Xbf -> HA ; layer 1: HA -> HB ; layer 2: HB -> HA
    const unsigned short* in0 = Xbf;
    unsigned short* outs[3] = { HA, HB, HA };
    for (int l = 0; l < 3; l++) {
        const unsigned short* xin = (l == 0) ? in0 : outs[l - 1];
        if (l == 0)
            k_aggmlp<false><<<MLP_BLOCKS, 256, 0, stream>>>(
                xin, nullptr, estart, eend, srcSorted,
                Wp + (size_t)(l * 2 + 0) * 16384, b1s + (size_t)l * HID,
                Wp + (size_t)(l * 2 + 1) * 16384, b2s + (size_t)l * HID, outs[l], bnpart);
        else
            k_aggmlp<true><<<MLP_BLOCKS, 256, 0, stream>>>(
                xin, bnsc, estart, eend, srcSorted,
                Wp + (size_t)(l * 2 + 0) * 16384, b1s + (size_t)l * HID,
                Wp + (size_t)(l * 2 + 1) * 16384, b2s + (size_t)l * HID, outs[l], bnpart);
        k_bnfin<<<64, 256, 0, stream>>>(bnpart, gammas + (size_t)l * HID,
                                        betas + (size_t)l * HID, bnred2, bnsc, doneBN);
    }

    k_poolfin<<<POOL_BLOCKS, 256, 0, stream>>>(outs[2], bnsc, batch, g, Wlin, blin, out, donePool);
}

// Round 10
// 334.668 us; speedup vs baseline: 1.3003x; 1.3003x over previous
//
#include <hip/hip_runtime.h>

#define N_NODES 50000
#define N_EDGES 800000
#define HID 128
#define OUTC 10
#define N_GRAPHS 64
#define BN_EPS 1e-5f

#define MLP_BLOCKS (N_NODES / 16)   // 3125, exact

// radix partition params
#define NB 196          // ceil(50000/256) buckets of 256 nodes
#define BCAP 5632       // per-bucket capacity (mean 4082, sigma~64; huge margin)
#define EPB 2048        // edges per phase-A block
#define NBLK_A ((N_EDGES + EPB - 1) / EPB)   // 391

typedef __attribute__((ext_vector_type(8))) short short8_t;
typedef __attribute__((ext_vector_type(4))) float f32x4;

__device__ __forceinline__ unsigned short f2bf(float f) {
    unsigned u = __float_as_uint(f);
    u += 0x7FFFu + ((u >> 16) & 1u);     // RNE
    return (unsigned short)(u >> 16);
}
__device__ __forceinline__ float bf2f(unsigned short s) {
    return __uint_as_float(((unsigned)s) << 16);
}
__device__ __forceinline__ float2 bfp2f(unsigned v) {
    float2 r;
    r.x = __uint_as_float(v << 16);
    r.y = __uint_as_float(v & 0xFFFF0000u);
    return r;
}

// ---------------- Phase A: bin edges into 196 coarse buckets ----------------
// ebuf entry: (dstLow8 << 16) | src16
__global__ __launch_bounds__(256) void k_bucket(const int* __restrict__ src,
                                                const int* __restrict__ dst,
                                                int* __restrict__ bucketCnt,
                                                unsigned* __restrict__ ebuf) {
    __shared__ int cnt[NB];
    __shared__ int base[NB];
    int t = threadIdx.x;
    for (int i = t; i < NB; i += 256) cnt[i] = 0;
    __syncthreads();
    int e0 = blockIdx.x * EPB;
    int e1 = e0 + EPB; if (e1 > N_EDGES) e1 = N_EDGES;
    for (int e = e0 + t; e < e1; e += 256)
        atomicAdd(&cnt[dst[e] >> 8], 1);
    __syncthreads();
    for (int i = t; i < NB; i += 256) {
        int c = cnt[i];
        base[i] = c ? atomicAdd(&bucketCnt[i], c) : 0;
        cnt[i] = 0;
    }
    __syncthreads();
    for (int e = e0 + t; e < e1; e += 256) {
        int d = dst[e];
        int s = src[e];
        int b = d >> 8;
        int r = atomicAdd(&cnt[b], 1);
        ebuf[(size_t)b * BCAP + base[b] + r] = ((unsigned)(d & 255) << 16) | (unsigned)s;
    }
}

// ---------------- Phase B: per-bucket local sort -> srcSorted + estart/eend ----------------
__global__ __launch_bounds__(256) void k_bsort(const int* __restrict__ bucketCnt,
                                               const unsigned* __restrict__ ebuf,
                                               unsigned short* __restrict__ srcSorted,
                                               int* __restrict__ estart,
                                               int* __restrict__ eend) {
    __shared__ int cnt[256];
    __shared__ int sh[256];
    __shared__ int pos[256];
    int b = blockIdx.x;
    int t = threadIdx.x;
    int n = bucketCnt[b];
    int bBase = b * BCAP;
    const unsigned* eb = ebuf + (size_t)bBase;
    cnt[t] = 0;
    __syncthreads();
    for (int i = t; i < n; i += 256) atomicAdd(&cnt[eb[i] >> 16], 1);
    __syncthreads();
    int v = cnt[t];
    sh[t] = v;
    __syncthreads();
    for (int off = 1; off < 256; off <<= 1) {
        int x = sh[t];
        if (t >= off) x += sh[t - off];
        __syncthreads();
        sh[t] = x;
        __syncthreads();
    }
    int excl = sh[t] - v;
    pos[t] = excl;
    int node = b * 256 + t;
    if (node < N_NODES) {
        estart[node] = bBase + excl;
        eend[node] = bBase + excl + v;
    }
    __syncthreads();
    for (int i = t; i < n; i += 256) {
        unsigned pe = eb[i];
        int dl = pe >> 16;
        int p = atomicAdd(&pos[dl], 1);
        srcSorted[bBase + p] = (unsigned short)(pe & 0xFFFFu);
    }
}

// ---------------- prep: x->bf16 cast + weight pre-pack ----------------
#define X2BF_ITEMS (N_NODES * HID / 8)   // 800000
__global__ void k_prep(const float* __restrict__ x, const float* __restrict__ W1s,
                       const float* __restrict__ W2s,
                       unsigned short* __restrict__ xbf, unsigned short* __restrict__ Wp) {
    int gid = blockIdx.x * 256 + threadIdx.x;
    if (gid < X2BF_ITEMS) {
        const float4* p = (const float4*)&x[(size_t)gid * 8];
        float4 a = p[0], b = p[1];
        short8_t o = { (short)f2bf(a.x), (short)f2bf(a.y), (short)f2bf(a.z), (short)f2bf(a.w),
                       (short)f2bf(b.x), (short)f2bf(b.y), (short)f2bf(b.z), (short)f2bf(b.w) };
        *(short8_t*)&xbf[(size_t)gid * 8] = o;
    } else {
        int idx = gid - X2BF_ITEMS;
        if (idx >= 6 * 2048) return;
        int mat = idx >> 11;
        int rem = idx & 2047;
        int lane = rem & 63;
        int ks = (rem >> 6) & 3;
        int nt = rem >> 8;
        int l = mat >> 1;
        const float* W = (mat & 1) ? (W2s + (size_t)l * HID * HID) : (W1s + (size_t)l * HID * HID);
        int n = nt * 16 + (lane & 15);
        int k0 = ks * 32 + (lane >> 4) * 8;
        short8_t o;
#pragma unroll
        for (int j = 0; j < 8; j++) o[j] = (short)f2bf(W[(size_t)(k0 + j) * HID + n]);
        *(short8_t*)&Wp[(size_t)idx * 8] = o;
    }
}

// ---------------- Fused aggregation + MFMA MLP ----------------
#define MPITCH 136

template <bool BN>
__global__ __launch_bounds__(256) void k_aggmlp(const unsigned short* __restrict__ X,
                                                const float* __restrict__ sc,
                                                const int* __restrict__ estart,
                                                const int* __restrict__ eend,
                                                const unsigned short* __restrict__ srcSorted,
                                                const unsigned short* __restrict__ W1p,
                                                const float* __restrict__ b1,
                                                const unsigned short* __restrict__ W2p,
                                                const float* __restrict__ b2,
                                                unsigned short* __restrict__ hbf,
                                                float* __restrict__ bnpart) {
    __shared__ __align__(16) unsigned short As[16 * MPITCH];
    __shared__ __align__(16) unsigned short Ts[16 * MPITCH];

    int tid = threadIdx.x;
    int wave = tid >> 6;
    int lane = tid & 63;
    int lrow = lane & 15;
    int quad = lane >> 4;
    int half = lane >> 5;
    int hl = lane & 31;
    int hq = hl >> 4;
    int rowBase = blockIdx.x * 16;
    int col0 = lrow * 8;

    float scv[8], shv[8];
    if (BN) {
#pragma unroll
        for (int j = 0; j < 8; j++) { scv[j] = sc[col0 + j]; shv[j] = sc[HID + col0 + j]; }
    }

    for (int pr = 0; pr < 2; pr++) {
        int tr = wave * 4 + pr * 2 + half;
        int node = rowBase + tr;
        float acc[8];
        {
            short8_t ov = *(const short8_t*)&X[(size_t)node * HID + col0];
            uint4 uu = *(uint4*)&ov;
            float2 p0 = bfp2f(uu.x), p1 = bfp2f(uu.y), p2 = bfp2f(uu.z), p3 = bfp2f(uu.w);
            float f[8] = { p0.x, p0.y, p1.x, p1.y, p2.x, p2.y, p3.x, p3.y };
#pragma unroll
            for (int j = 0; j < 8; j++) {
                float v = BN ? fmaxf(f[j] * scv[j] + shv[j], 0.f) : f[j];
                acc[j] = (hq == 0) ? v : 0.f;
            }
        }

        int e0 = estart[node];
        int deg = eend[node] - e0;

        for (int base = 0; base < deg; base += 16) {
            int cnt = deg - base; if (cnt > 16) cnt = 16;
            int ipos = base + (hl & 15); if (ipos >= deg) ipos = deg - 1;
            int myidx = (int)srcSorted[e0 + ipos];

            short8_t v[8];
#pragma unroll
            for (int u = 0; u < 8; u++) {
                int slot = u * 2 + hq;
                int sl = slot < cnt ? slot : cnt - 1;
                int ridx = __shfl(myidx, (half << 5) + sl);
                v[u] = *(const short8_t*)&X[(size_t)ridx * HID + col0];
            }
#pragma unroll
            for (int u = 0; u < 8; u++) {
                int slot = u * 2 + hq;
                if (slot < cnt) {
                    uint4 uu = *(uint4*)&v[u];
                    float2 p0 = bfp2f(uu.x), p1 = bfp2f(uu.y), p2 = bfp2f(uu.z), p3 = bfp2f(uu.w);
                    float f[8] = { p0.x, p0.y, p1.x, p1.y, p2.x, p2.y, p3.x, p3.y };
#pragma unroll
                    for (int j = 0; j < 8; j++)
                        acc[j] += BN ? fmaxf(f[j] * scv[j] + shv[j], 0.f) : f[j];
                }
            }
        }

#pragma unroll
        for (int j = 0; j < 8; j++) acc[j] += __shfl_xor(acc[j], 16);
        if (hq == 0) {
            short8_t o;
#pragma unroll
            for (int j = 0; j < 8; j++) o[j] = (short)f2bf(acc[j]);
            *(short8_t*)&As[tr * MPITCH + col0] = o;
        }
    }
    __syncthreads();

    int t0 = wave * 2;
    short8_t a0f = *(const short8_t*)&As[lrow * MPITCH + 0 * 32 + quad * 8];
    short8_t a1f = *(const short8_t*)&As[lrow * MPITCH + 1 * 32 + quad * 8];
    short8_t a2f = *(const short8_t*)&As[lrow * MPITCH + 2 * 32 + quad * 8];
    short8_t a3f = *(const short8_t*)&As[lrow * MPITCH + 3 * 32 + quad * 8];

    f32x4 acc1[2];
#pragma unroll
    for (int ti = 0; ti < 2; ti++) {
        int t = t0 + ti;
        f32x4 a = (f32x4){ 0.f, 0.f, 0.f, 0.f };
        short8_t b0 = *(const short8_t*)&W1p[(size_t)((t * 4 + 0) * 64 + lane) * 8];
        short8_t b1_ = *(const short8_t*)&W1p[(size_t)((t * 4 + 1) * 64 + lane) * 8];
        short8_t b2_ = *(const short8_t*)&W1p[(size_t)((t * 4 + 2) * 64 + lane) * 8];
        short8_t b3 = *(const short8_t*)&W1p[(size_t)((t * 4 + 3) * 64 + lane) * 8];
        a = __builtin_amdgcn_mfma_f32_16x16x32_bf16(a0f, b0, a, 0, 0, 0);
        a = __builtin_amdgcn_mfma_f32_16x16x32_bf16(a1f, b1_, a, 0, 0, 0);
        a = __builtin_amdgcn_mfma_f32_16x16x32_bf16(a2f, b2_, a, 0, 0, 0);
        a = __builtin_amdgcn_mfma_f32_16x16x32_bf16(a3f, b3, a, 0, 0, 0);
        acc1[ti] = a;
    }

#pragma unroll
    for (int ti = 0; ti < 2; ti++) {
        int col = (t0 + ti) * 16 + lrow;
        float bb = b1[col];
#pragma unroll
        for (int r = 0; r < 4; r++) {
            float v = fmaxf(acc1[ti][r] + bb, 0.f);
            Ts[(quad * 4 + r) * MPITCH + col] = f2bf(v);
        }
    }
    __syncthreads();

    short8_t t0f = *(const short8_t*)&Ts[lrow * MPITCH + 0 * 32 + quad * 8];
    short8_t t1f = *(const short8_t*)&Ts[lrow * MPITCH + 1 * 32 + quad * 8];
    short8_t t2f = *(const short8_t*)&Ts[lrow * MPITCH + 2 * 32 + quad * 8];
    short8_t t3f = *(const short8_t*)&Ts[lrow * MPITCH + 3 * 32 + quad * 8];

    f32x4 acc2[2];
#pragma unroll
    for (int ti = 0; ti < 2; ti++) {
        int t = t0 + ti;
        f32x4 a = (f32x4){ 0.f, 0.f, 0.f, 0.f };
        short8_t b0 = *(const short8_t*)&W2p[(size_t)((t * 4 + 0) * 64 + lane) * 8];
        short8_t b1_ = *(const short8_t*)&W2p[(size_t)((t * 4 + 1) * 64 + lane) * 8];
        short8_t b2_ = *(const short8_t*)&W2p[(size_t)((t * 4 + 2) * 64 + lane) * 8];
        short8_t b3 = *(const short8_t*)&W2p[(size_t)((t * 4 + 3) * 64 + lane) * 8];
        a = __builtin_amdgcn_mfma_f32_16x16x32_bf16(t0f, b0, a, 0, 0, 0);
        a = __builtin_amdgcn_mfma_f32_16x16x32_bf16(t1f, b1_, a, 0, 0, 0);
        a = __builtin_amdgcn_mfma_f32_16x16x32_bf16(t2f, b2_, a, 0, 0, 0);
        a = __builtin_amdgcn_mfma_f32_16x16x32_bf16(t3f, b3, a, 0, 0, 0);
        acc2[ti] = a;
    }

#pragma unroll
    for (int ti = 0; ti < 2; ti++) {
        int t = t0 + ti;
        int col = t * 16 + lrow;
        float bb = b2[col];
        float p1 = 0.f, p2 = 0.f;
#pragma unroll
        for (int r = 0; r < 4; r++) {
            unsigned short bv = f2bf(acc2[ti][r] + bb);
            float vr = bf2f(bv);
            p1 += vr; p2 += vr * vr;
            As[(quad * 4 + r) * MPITCH + col] = bv;
        }
        p1 += __shfl_xor(p1, 16); p1 += __shfl_xor(p1, 32);
        p2 += __shfl_xor(p2, 16); p2 += __shfl_xor(p2, 32);
        if (quad == 0) {
            float* bp = bnpart + (size_t)blockIdx.x * 256;
            bp[t * 16 + lrow] = p1;
            bp[128 + t * 16 + lrow] = p2;
        }
    }
    __syncthreads();

    {
        int r = tid >> 4;
        int c8 = (tid & 15) * 8;
        *(short8_t*)&hbf[(size_t)(rowBase + r) * HID + c8] =
            *(const short8_t*)&As[r * MPITCH + c8];
    }
}

// ---------------- BN partial reduce (separate kernels; boundaries = visibility) ----------------
__global__ void k_bnred(const float* __restrict__ bnpart, float* __restrict__ bnred2) {
    float acc = 0.f;
    for (int r = blockIdx.x; r < MLP_BLOCKS; r += 64)
        acc += bnpart[(size_t)r * 256 + threadIdx.x];
    bnred2[blockIdx.x * 256 + threadIdx.x] = acc;
}

__global__ void k_bnscale(const float* __restrict__ bnred2, const float* __restrict__ gamma,
                          const float* __restrict__ beta, float* __restrict__ sc) {
    __shared__ float tot[256];
    int t = threadIdx.x;
    float a = 0.f;
    for (int j = 0; j < 64; j++) a += bnred2[j * 256 + t];
    tot[t] = a;
    __syncthreads();
    if (t < HID) {
        float mean = tot[t] * (1.0f / N_NODES);
        float var = tot[HID + t] * (1.0f / N_NODES) - mean * mean;
        float s = gamma[t] * rsqrtf(var + BN_EPS);
        sc[t] = s;
        sc[HID + t] = beta[t] - mean * s;
    }
}

// ---------------- Pool with fused BN+ReLU (batch sorted) ----------------
#define POOL_CHUNK 512
__global__ void k_pool(const unsigned short* __restrict__ X, const float* __restrict__ sc,
                       const int* __restrict__ batch, float* __restrict__ g) {
    int lane = threadIdx.x & 31;
    int rg = threadIdx.x >> 5;
    int c = lane * 4;
    float4 s = *(const float4*)&sc[c];
    float4 b = *(const float4*)&sc[HID + c];
    int base = blockIdx.x * POOL_CHUNK;
    int end = base + POOL_CHUNK;
    if (end > N_NODES) end = N_NODES;
    float a0 = 0.f, a1 = 0.f, a2 = 0.f, a3 = 0.f;
    int cur = -1;
    for (int r = base + rg; r < end; r += 8) {
        int bb = batch[r];
        if (bb != cur) {
            if (cur >= 0) {
                atomicAdd(&g[cur * HID + c + 0], a0);
                atomicAdd(&g[cur * HID + c + 1], a1);
                atomicAdd(&g[cur * HID + c + 2], a2);
                atomicAdd(&g[cur * HID + c + 3], a3);
            }
            cur = bb;
            a0 = a1 = a2 = a3 = 0.f;
        }
        ushort4 v = *(const ushort4*)&X[(size_t)r * HID + c];
        a0 += fmaxf(bf2f(v.x) * s.x + b.x, 0.f);
        a1 += fmaxf(bf2f(v.y) * s.y + b.y, 0.f);
        a2 += fmaxf(bf2f(v.z) * s.z + b.z, 0.f);
        a3 += fmaxf(bf2f(v.w) * s.w + b.w, 0.f);
    }
    if (cur >= 0) {
        atomicAdd(&g[cur * HID + c + 0], a0);
        atomicAdd(&g[cur * HID + c + 1], a1);
        atomicAdd(&g[cur * HID + c + 2], a2);
        atomicAdd(&g[cur * HID + c + 3], a3);
    }
}

// ---------------- Final linear ----------------
__global__ void k_final(const float* __restrict__ g, const float* __restrict__ Wlin,
                        const float* __restrict__ blin, float* __restrict__ out) {
    int o = blockIdx.x * 256 + threadIdx.x;
    if (o >= N_GRAPHS * OUTC) return;
    int gi = o / OUTC, c = o % OUTC;
    float s = blin[c];
    for (int k = 0; k < HID; k++) s += g[gi * HID + k] * Wlin[k * OUTC + c];
    out[o] = s;
}

// ---------------- Launch ----------------
extern "C" void kernel_launch(void* const* d_in, const int* in_sizes, int n_in,
                              void* d_out, int out_size, void* d_ws, size_t ws_size,
                              hipStream_t stream) {
    const float* x      = (const float*)d_in[0];
    const float* W1s    = (const float*)d_in[1];
    const float* b1s    = (const float*)d_in[2];
    const float* W2s    = (const float*)d_in[3];
    const float* b2s    = (const float*)d_in[4];
    const float* gammas = (const float*)d_in[5];
    const float* betas  = (const float*)d_in[6];
    const float* Wlin   = (const float*)d_in[7];
    const float* blin   = (const float*)d_in[8];
    const int* edge_index = (const int*)d_in[9];
    const int* batch    = (const int*)d_in[10];
    float* out = (float*)d_out;

    const int* src = edge_index;
    const int* dst = edge_index + N_EDGES;

    char* w = (char*)d_ws;
    int* bucketCnt = (int*)w;        w += 256 * 4;
    unsigned* ebuf = (unsigned*)w;   w += (size_t)NB * BCAP * 4;         // 4.4 MB
    unsigned short* srcSorted = (unsigned short*)w; w += (size_t)NB * BCAP * 2; // 2.2 MB
    int* estart    = (int*)w;        w += (size_t)N_NODES * 4;
    int* eend      = (int*)w;        w += (size_t)N_NODES * 4;
    unsigned short* Xbf = (unsigned short*)w; w += (size_t)N_NODES * HID * 2;   // 12.8 MB
    unsigned short* HA  = (unsigned short*)w; w += (size_t)N_NODES * HID * 2;
    unsigned short* HB  = (unsigned short*)w; w += (size_t)N_NODES * HID * 2;
    unsigned short* Wp  = (unsigned short*)w; w += (size_t)6 * 2048 * 8 * 2;
    float* bnpart = (float*)w; w += (size_t)MLP_BLOCKS * 256 * 4;        // 3.2 MB
    float* bnred2 = (float*)w; w += (size_t)64 * 256 * 4;
    float* bnsc   = (float*)w; w += 2 * HID * 4;
    float* g      = (float*)w; w += (size_t)N_GRAPHS * HID * 4;

    hipMemsetAsync(bucketCnt, 0, 256 * 4, stream);
    hipMemsetAsync(g, 0, (size_t)N_GRAPHS * HID * 4, stream);

    k_bucket<<<NBLK_A, 256, 0, stream>>>(src, dst, bucketCnt, ebuf);
    k_bsort<<<NB, 256, 0, stream>>>(bucketCnt, ebuf, srcSorted, estart, eend);
    k_prep<<<(X2BF_ITEMS + 6 * 2048 + 255) / 256, 256, 0, stream>>>(x, W1s, W2s, Xbf, Wp);

    // layer 0: Xbf -> HA ; layer 1: HA -> HB ; layer 2: HB -> HA
    const unsigned short* in0 = Xbf;
    unsigned short* outs[3] = { HA, HB, HA };
    for (int l = 0; l < 3; l++) {
        const unsigned short* xin = (l == 0) ? in0 : outs[l - 1];
        if (l == 0)
            k_aggmlp<false><<<MLP_BLOCKS, 256, 0, stream>>>(
                xin, nullptr, estart, eend, srcSorted,
                Wp + (size_t)(l * 2 + 0) * 16384, b1s + (size_t)l * HID,
                Wp + (size_t)(l * 2 + 1) * 16384, b2s + (size_t)l * HID, outs[l], bnpart);
        else
            k_aggmlp<true><<<MLP_BLOCKS, 256, 0, stream>>>(
                xin, bnsc, estart, eend, srcSorted,
                Wp + (size_t)(l * 2 + 0) * 16384, b1s + (size_t)l * HID,
                Wp + (size_t)(l * 2 + 1) * 16384, b2s + (size_t)l * HID, outs[l], bnpart);
        k_bnred<<<64, 256, 0, stream>>>(bnpart, bnred2);
        k_bnscale<<<1, 256, 0, stream>>>(bnred2, gammas + (size_t)l * HID,
                                         betas + (size_t)l * HID, bnsc);
    }

    k_pool<<<(N_NODES + POOL_CHUNK - 1) / POOL_CHUNK, 256, 0, stream>>>(outs[2], bnsc, batch, g);
    k_final<<<(N_GRAPHS * OUTC + 255) / 256, 256, 0, stream>>>(g, Wlin, blin, out);
}

// Round 11
// 289.340 us; speedup vs baseline: 1.5040x; 1.1567x over previous
//
#include <hip/hip_runtime.h>

#define N_NODES 50000
#define N_EDGES 800000
#define HID 128
#define OUTC 10
#define N_GRAPHS 64
#define BN_EPS 1e-5f

#define MLP_BLOCKS (N_NODES / 16)   // 3125, exact

// radix partition params
#define NB 196          // ceil(50000/256) buckets of 256 nodes
#define BCAP 5632       // per-bucket capacity (mean 4082; huge margin)
#define EPB 2048        // edges per phase-A block
#define NBLK_A ((N_EDGES + EPB - 1) / EPB)   // 391

#define X2BF_ITEMS (N_NODES * HID / 8)           // 800000
#define PREP_ITEMS (X2BF_ITEMS + 6 * 2048)       // + weight frags
#define NBLK_PREP ((PREP_ITEMS + 255) / 256)     // 3173

typedef __attribute__((ext_vector_type(8))) short short8_t;
typedef __attribute__((ext_vector_type(4))) float f32x4;

__device__ __forceinline__ unsigned short f2bf(float f) {
    unsigned u = __float_as_uint(f);
    u += 0x7FFFu + ((u >> 16) & 1u);     // RNE
    return (unsigned short)(u >> 16);
}
__device__ __forceinline__ float bf2f(unsigned short s) {
    return __uint_as_float(((unsigned)s) << 16);
}
__device__ __forceinline__ float2 bfp2f(unsigned v) {
    float2 r;
    r.x = __uint_as_float(v << 16);
    r.y = __uint_as_float(v & 0xFFFF0000u);
    return r;
}

// ---------------- Fused: phase-A bucket binning + (x->bf16, weight pre-pack) ----------------
// blockIdx < NBLK_A: bin 2048 edges into coarse buckets (dst>>8), ebuf=(dstLow8<<16)|src16
// else: prep work item
__global__ __launch_bounds__(256) void k_bucketprep(const int* __restrict__ src,
                                                    const int* __restrict__ dst,
                                                    int* __restrict__ bucketCnt,
                                                    unsigned* __restrict__ ebuf,
                                                    const float* __restrict__ x,
                                                    const float* __restrict__ W1s,
                                                    const float* __restrict__ W2s,
                                                    unsigned short* __restrict__ xbf,
                                                    unsigned short* __restrict__ Wp) {
    int t = threadIdx.x;
    if (blockIdx.x < NBLK_A) {
        __shared__ int cnt[NB];
        __shared__ int base[NB];
        for (int i = t; i < NB; i += 256) cnt[i] = 0;
        __syncthreads();
        int e0 = blockIdx.x * EPB;
        int e1 = e0 + EPB; if (e1 > N_EDGES) e1 = N_EDGES;
        for (int e = e0 + t; e < e1; e += 256)
            atomicAdd(&cnt[dst[e] >> 8], 1);
        __syncthreads();
        for (int i = t; i < NB; i += 256) {
            int c = cnt[i];
            base[i] = c ? atomicAdd(&bucketCnt[i], c) : 0;
            cnt[i] = 0;
        }
        __syncthreads();
        for (int e = e0 + t; e < e1; e += 256) {
            int d = dst[e];
            int s = src[e];
            int b = d >> 8;
            int r = atomicAdd(&cnt[b], 1);
            ebuf[(size_t)b * BCAP + base[b] + r] = ((unsigned)(d & 255) << 16) | (unsigned)s;
        }
    } else {
        int gid = (blockIdx.x - NBLK_A) * 256 + t;
        if (gid < X2BF_ITEMS) {
            const float4* p = (const float4*)&x[(size_t)gid * 8];
            float4 a = p[0], b = p[1];
            short8_t o = { (short)f2bf(a.x), (short)f2bf(a.y), (short)f2bf(a.z), (short)f2bf(a.w),
                           (short)f2bf(b.x), (short)f2bf(b.y), (short)f2bf(b.z), (short)f2bf(b.w) };
            *(short8_t*)&xbf[(size_t)gid * 8] = o;
        } else {
            int idx = gid - X2BF_ITEMS;
            if (idx >= 6 * 2048) return;
            int mat = idx >> 11;
            int rem = idx & 2047;
            int lane = rem & 63;
            int ks = (rem >> 6) & 3;
            int nt = rem >> 8;
            int l = mat >> 1;
            const float* W = (mat & 1) ? (W2s + (size_t)l * HID * HID) : (W1s + (size_t)l * HID * HID);
            int n = nt * 16 + (lane & 15);
            int k0 = ks * 32 + (lane >> 4) * 8;
            short8_t o;
#pragma unroll
            for (int j = 0; j < 8; j++) o[j] = (short)f2bf(W[(size_t)(k0 + j) * HID + n]);
            *(short8_t*)&Wp[(size_t)idx * 8] = o;
        }
    }
}

// ---------------- Phase B: per-bucket local sort -> srcSorted + estart/eend ----------------
__global__ __launch_bounds__(256) void k_bsort(const int* __restrict__ bucketCnt,
                                               const unsigned* __restrict__ ebuf,
                                               unsigned short* __restrict__ srcSorted,
                                               int* __restrict__ estart,
                                               int* __restrict__ eend) {
    __shared__ int cnt[256];
    __shared__ int sh[256];
    __shared__ int pos[256];
    int b = blockIdx.x;
    int t = threadIdx.x;
    int n = bucketCnt[b];
    int bBase = b * BCAP;
    const unsigned* eb = ebuf + (size_t)bBase;
    cnt[t] = 0;
    __syncthreads();
    for (int i = t; i < n; i += 256) atomicAdd(&cnt[eb[i] >> 16], 1);
    __syncthreads();
    int v = cnt[t];
    sh[t] = v;
    __syncthreads();
    for (int off = 1; off < 256; off <<= 1) {
        int x = sh[t];
        if (t >= off) x += sh[t - off];
        __syncthreads();
        sh[t] = x;
        __syncthreads();
    }
    int excl = sh[t] - v;
    pos[t] = excl;
    int node = b * 256 + t;
    if (node < N_NODES) {
        estart[node] = bBase + excl;
        eend[node] = bBase + excl + v;
    }
    __syncthreads();
    for (int i = t; i < n; i += 256) {
        unsigned pe = eb[i];
        int dl = pe >> 16;
        int p = atomicAdd(&pos[dl], 1);
        srcSorted[bBase + p] = (unsigned short)(pe & 0xFFFFu);
    }
}

// ---------------- Fused aggregation + MFMA MLP ----------------
#define MPITCH 136

template <bool BN>
__global__ __launch_bounds__(256) void k_aggmlp(const unsigned short* __restrict__ X,
                                                const float* __restrict__ sc,
                                                const int* __restrict__ estart,
                                                const int* __restrict__ eend,
                                                const unsigned short* __restrict__ srcSorted,
                                                const unsigned short* __restrict__ W1p,
                                                const float* __restrict__ b1,
                                                const unsigned short* __restrict__ W2p,
                                                const float* __restrict__ b2,
                                                unsigned short* __restrict__ hbf,
                                                float* __restrict__ bnpart) {
    __shared__ __align__(16) unsigned short As[16 * MPITCH];
    __shared__ __align__(16) unsigned short Ts[16 * MPITCH];

    int tid = threadIdx.x;
    int wave = tid >> 6;
    int lane = tid & 63;
    int lrow = lane & 15;
    int quad = lane >> 4;
    int half = lane >> 5;
    int hl = lane & 31;
    int hq = hl >> 4;
    int rowBase = blockIdx.x * 16;
    int col0 = lrow * 8;

    float scv[8], shv[8];
    if (BN) {
#pragma unroll
        for (int j = 0; j < 8; j++) { scv[j] = sc[col0 + j]; shv[j] = sc[HID + col0 + j]; }
    }

    for (int pr = 0; pr < 2; pr++) {
        int tr = wave * 4 + pr * 2 + half;
        int node = rowBase + tr;
        float acc[8];
        {
            short8_t ov = *(const short8_t*)&X[(size_t)node * HID + col0];
            uint4 uu = *(uint4*)&ov;
            float2 p0 = bfp2f(uu.x), p1 = bfp2f(uu.y), p2 = bfp2f(uu.z), p3 = bfp2f(uu.w);
            float f[8] = { p0.x, p0.y, p1.x, p1.y, p2.x, p2.y, p3.x, p3.y };
#pragma unroll
            for (int j = 0; j < 8; j++) {
                float v = BN ? fmaxf(f[j] * scv[j] + shv[j], 0.f) : f[j];
                acc[j] = (hq == 0) ? v : 0.f;
            }
        }

        int e0 = estart[node];
        int deg = eend[node] - e0;

        for (int base = 0; base < deg; base += 16) {
            int cnt = deg - base; if (cnt > 16) cnt = 16;
            int ipos = base + (hl & 15); if (ipos >= deg) ipos = deg - 1;
            int myidx = (int)srcSorted[e0 + ipos];

            short8_t v[8];
#pragma unroll
            for (int u = 0; u < 8; u++) {
                int slot = u * 2 + hq;
                int sl = slot < cnt ? slot : cnt - 1;
                int ridx = __shfl(myidx, (half << 5) + sl);
                v[u] = *(const short8_t*)&X[(size_t)ridx * HID + col0];
            }
#pragma unroll
            for (int u = 0; u < 8; u++) {
                int slot = u * 2 + hq;
                if (slot < cnt) {
                    uint4 uu = *(uint4*)&v[u];
                    float2 p0 = bfp2f(uu.x), p1 = bfp2f(uu.y), p2 = bfp2f(uu.z), p3 = bfp2f(uu.w);
                    float f[8] = { p0.x, p0.y, p1.x, p1.y, p2.x, p2.y, p3.x, p3.y };
#pragma unroll
                    for (int j = 0; j < 8; j++)
                        acc[j] += BN ? fmaxf(f[j] * scv[j] + shv[j], 0.f) : f[j];
                }
            }
        }

#pragma unroll
        for (int j = 0; j < 8; j++) acc[j] += __shfl_xor(acc[j], 16);
        if (hq == 0) {
            short8_t o;
#pragma unroll
            for (int j = 0; j < 8; j++) o[j] = (short)f2bf(acc[j]);
            *(short8_t*)&As[tr * MPITCH + col0] = o;
        }
    }
    __syncthreads();

    int t0 = wave * 2;
    short8_t a0f = *(const short8_t*)&As[lrow * MPITCH + 0 * 32 + quad * 8];
    short8_t a1f = *(const short8_t*)&As[lrow * MPITCH + 1 * 32 + quad * 8];
    short8_t a2f = *(const short8_t*)&As[lrow * MPITCH + 2 * 32 + quad * 8];
    short8_t a3f = *(const short8_t*)&As[lrow * MPITCH + 3 * 32 + quad * 8];

    f32x4 acc1[2];
#pragma unroll
    for (int ti = 0; ti < 2; ti++) {
        int t = t0 + ti;
        f32x4 a = (f32x4){ 0.f, 0.f, 0.f, 0.f };
        short8_t b0 = *(const short8_t*)&W1p[(size_t)((t * 4 + 0) * 64 + lane) * 8];
        short8_t b1_ = *(const short8_t*)&W1p[(size_t)((t * 4 + 1) * 64 + lane) * 8];
        short8_t b2_ = *(const short8_t*)&W1p[(size_t)((t * 4 + 2) * 64 + lane) * 8];
        short8_t b3 = *(const short8_t*)&W1p[(size_t)((t * 4 + 3) * 64 + lane) * 8];
        a = __builtin_amdgcn_mfma_f32_16x16x32_bf16(a0f, b0, a, 0, 0, 0);
        a = __builtin_amdgcn_mfma_f32_16x16x32_bf16(a1f, b1_, a, 0, 0, 0);
        a = __builtin_amdgcn_mfma_f32_16x16x32_bf16(a2f, b2_, a, 0, 0, 0);
        a = __builtin_amdgcn_mfma_f32_16x16x32_bf16(a3f, b3, a, 0, 0, 0);
        acc1[ti] = a;
    }

#pragma unroll
    for (int ti = 0; ti < 2; ti++) {
        int col = (t0 + ti) * 16 + lrow;
        float bb = b1[col];
#pragma unroll
        for (int r = 0; r < 4; r++) {
            float v = fmaxf(acc1[ti][r] + bb, 0.f);
            Ts[(quad * 4 + r) * MPITCH + col] = f2bf(v);
        }
    }
    __syncthreads();

    short8_t t0f = *(const short8_t*)&Ts[lrow * MPITCH + 0 * 32 + quad * 8];
    short8_t t1f = *(const short8_t*)&Ts[lrow * MPITCH + 1 * 32 + quad * 8];
    short8_t t2f = *(const short8_t*)&Ts[lrow * MPITCH + 2 * 32 + quad * 8];
    short8_t t3f = *(const short8_t*)&Ts[lrow * MPITCH + 3 * 32 + quad * 8];

    f32x4 acc2[2];
#pragma unroll
    for (int ti = 0; ti < 2; ti++) {
        int t = t0 + ti;
        f32x4 a = (f32x4){ 0.f, 0.f, 0.f, 0.f };
        short8_t b0 = *(const short8_t*)&W2p[(size_t)((t * 4 + 0) * 64 + lane) * 8];
        short8_t b1_ = *(const short8_t*)&W2p[(size_t)((t * 4 + 1) * 64 + lane) * 8];
        short8_t b2_ = *(const short8_t*)&W2p[(size_t)((t * 4 + 2) * 64 + lane) * 8];
        short8_t b3 = *(const short8_t*)&W2p[(size_t)((t * 4 + 3) * 64 + lane) * 8];
        a = __builtin_amdgcn_mfma_f32_16x16x32_bf16(t0f, b0, a, 0, 0, 0);
        a = __builtin_amdgcn_mfma_f32_16x16x32_bf16(t1f, b1_, a, 0, 0, 0);
        a = __builtin_amdgcn_mfma_f32_16x16x32_bf16(t2f, b2_, a, 0, 0, 0);
        a = __builtin_amdgcn_mfma_f32_16x16x32_bf16(t3f, b3, a, 0, 0, 0);
        acc2[ti] = a;
    }

#pragma unroll
    for (int ti = 0; ti < 2; ti++) {
        int t = t0 + ti;
        int col = t * 16 + lrow;
        float bb = b2[col];
        float p1 = 0.f, p2 = 0.f;
#pragma unroll
        for (int r = 0; r < 4; r++) {
            unsigned short bv = f2bf(acc2[ti][r] + bb);
            float vr = bf2f(bv);
            p1 += vr; p2 += vr * vr;
            As[(quad * 4 + r) * MPITCH + col] = bv;
        }
        p1 += __shfl_xor(p1, 16); p1 += __shfl_xor(p1, 32);
        p2 += __shfl_xor(p2, 16); p2 += __shfl_xor(p2, 32);
        if (quad == 0) {
            float* bp = bnpart + (size_t)(blockIdx.x & 63) * 256;
            atomicAdd(&bp[col], p1);
            atomicAdd(&bp[128 + col], p2);
        }
    }
    __syncthreads();

    {
        int r = tid >> 4;
        int c8 = (tid & 15) * 8;
        *(short8_t*)&hbf[(size_t)(rowBase + r) * HID + c8] =
            *(const short8_t*)&As[r * MPITCH + c8];
    }
}

// ---------------- BN finalize: reduce 64x256 slots -> sc; re-zero slots; zero g ----------------
__global__ void k_bnscale2(float* __restrict__ bnpart, const float* __restrict__ gamma,
                           const float* __restrict__ beta, float* __restrict__ sc,
                           float* __restrict__ g) {
    __shared__ float tot[256];
    int t = threadIdx.x;
    float a = 0.f;
    for (int j = 0; j < 64; j++) a += bnpart[j * 256 + t];
    tot[t] = a;
    for (int j = 0; j < 64; j++) bnpart[j * 256 + t] = 0.f;   // ready for next layer
    for (int i = t; i < N_GRAPHS * HID; i += 256) g[i] = 0.f; // ready for pool
    __syncthreads();
    if (t < HID) {
        float mean = tot[t] * (1.0f / N_NODES);
        float var = tot[HID + t] * (1.0f / N_NODES) - mean * mean;
        float s = gamma[t] * rsqrtf(var + BN_EPS);
        sc[t] = s;
        sc[HID + t] = beta[t] - mean * s;
    }
}

// ---------------- Pool with fused BN+ReLU (batch sorted) ----------------
#define POOL_CHUNK 512
__global__ void k_pool(const unsigned short* __restrict__ X, const float* __restrict__ sc,
                       const int* __restrict__ batch, float* __restrict__ g) {
    int lane = threadIdx.x & 31;
    int rg = threadIdx.x >> 5;
    int c = lane * 4;
    float4 s = *(const float4*)&sc[c];
    float4 b = *(const float4*)&sc[HID + c];
    int base = blockIdx.x * POOL_CHUNK;
    int end = base + POOL_CHUNK;
    if (end > N_NODES) end = N_NODES;
    float a0 = 0.f, a1 = 0.f, a2 = 0.f, a3 = 0.f;
    int cur = -1;
    for (int r = base + rg; r < end; r += 8) {
        int bb = batch[r];
        if (bb != cur) {
            if (cur >= 0) {
                atomicAdd(&g[cur * HID + c + 0], a0);
                atomicAdd(&g[cur * HID + c + 1], a1);
                atomicAdd(&g[cur * HID + c + 2], a2);
                atomicAdd(&g[cur * HID + c + 3], a3);
            }
            cur = bb;
            a0 = a1 = a2 = a3 = 0.f;
        }
        ushort4 v = *(const ushort4*)&X[(size_t)r * HID + c];
        a0 += fmaxf(bf2f(v.x) * s.x + b.x, 0.f);
        a1 += fmaxf(bf2f(v.y) * s.y + b.y, 0.f);
        a2 += fmaxf(bf2f(v.z) * s.z + b.z, 0.f);
        a3 += fmaxf(bf2f(v.w) * s.w + b.w, 0.f);
    }
    if (cur >= 0) {
        atomicAdd(&g[cur * HID + c + 0], a0);
        atomicAdd(&g[cur * HID + c + 1], a1);
        atomicAdd(&g[cur * HID + c + 2], a2);
        atomicAdd(&g[cur * HID + c + 3], a3);
    }
}

// ---------------- Final linear ----------------
__global__ void k_final(const float* __restrict__ g, const float* __restrict__ Wlin,
                        const float* __restrict__ blin, float* __restrict__ out) {
    int o = blockIdx.x * 256 + threadIdx.x;
    if (o >= N_GRAPHS * OUTC) return;
    int gi = o / OUTC, c = o % OUTC;
    float s = blin[c];
    for (int k = 0; k < HID; k++) s += g[gi * HID + k] * Wlin[k * OUTC + c];
    out[o] = s;
}

// ---------------- Launch ----------------
extern "C" void kernel_launch(void* const* d_in, const int* in_sizes, int n_in,
                              void* d_out, int out_size, void* d_ws, size_t ws_size,
                              hipStream_t stream) {
    const float* x      = (const float*)d_in[0];
    const float* W1s    = (const float*)d_in[1];
    const float* b1s    = (const float*)d_in[2];
    const float* W2s    = (const float*)d_in[3];
    const float* b2s    = (const float*)d_in[4];
    const float* gammas = (const float*)d_in[5];
    const float* betas  = (const float*)d_in[6];
    const float* Wlin   = (const float*)d_in[7];
    const float* blin   = (const float*)d_in[8];
    const int* edge_index = (const int*)d_in[9];
    const int* batch    = (const int*)d_in[10];
    float* out = (float*)d_out;

    const int* src = edge_index;
    const int* dst = edge_index + N_EDGES;

    char* w = (char*)d_ws;
    int* bucketCnt = (int*)w;        w += 256 * 4;                       // 1 KB
    float* bnpart  = (float*)w;      w += (size_t)64 * 256 * 4;          // 64 KB (contiguous with bucketCnt for one memset)
    unsigned* ebuf = (unsigned*)w;   w += (size_t)NB * BCAP * 4;         // 4.4 MB
    unsigned short* srcSorted = (unsigned short*)w; w += (size_t)NB * BCAP * 2; // 2.2 MB
    int* estart    = (int*)w;        w += (size_t)N_NODES * 4;
    int* eend      = (int*)w;        w += (size_t)N_NODES * 4;
    unsigned short* Xbf = (unsigned short*)w; w += (size_t)N_NODES * HID * 2;   // 12.8 MB
    unsigned short* HA  = (unsigned short*)w; w += (size_t)N_NODES * HID * 2;
    unsigned short* HB  = (unsigned short*)w; w += (size_t)N_NODES * HID * 2;
    unsigned short* Wp  = (unsigned short*)w; w += (size_t)6 * 2048 * 8 * 2;
    float* bnsc   = (float*)w; w += 2 * HID * 4;
    float* g      = (float*)w; w += (size_t)N_GRAPHS * HID * 4;

    // one memset covers bucketCnt + bnpart (contiguous)
    hipMemsetAsync(bucketCnt, 0, 256 * 4 + 64 * 256 * 4, stream);

    k_bucketprep<<<NBLK_A + NBLK_PREP, 256, 0, stream>>>(src, dst, bucketCnt, ebuf,
                                                         x, W1s, W2s, Xbf, Wp);
    k_bsort<<<NB, 256, 0, stream>>>(bucketCnt, ebuf, srcSorted, estart, eend);

    // layer 0: Xbf -> HA ; layer 1: HA -> HB ; layer 2: HB -> HA
    const unsigned short* in0 = Xbf;
    unsigned short* outs[3] = { HA, HB, HA };
    for (int l = 0; l < 3; l++) {
        const unsigned short* xin = (l == 0) ? in0 : outs[l - 1];
        if (l == 0)
            k_aggmlp<false><<<MLP_BLOCKS, 256, 0, stream>>>(
                xin, nullptr, estart, eend, srcSorted,
                Wp + (size_t)(l * 2 + 0) * 16384, b1s + (size_t)l * HID,
                Wp + (size_t)(l * 2 + 1) * 16384, b2s + (size_t)l * HID, outs[l], bnpart);
        else
            k_aggmlp<true><<<MLP_BLOCKS, 256, 0, stream>>>(
                xin, bnsc, estart, eend, srcSorted,
                Wp + (size_t)(l * 2 + 0) * 16384, b1s + (size_t)l * HID,
                Wp + (size_t)(l * 2 + 1) * 16384, b2s + (size_t)l * HID, outs[l], bnpart);
        k_bnscale2<<<1, 256, 0, stream>>>(bnpart, gammas + (size_t)l * HID,
                                          betas + (size_t)l * HID, bnsc, g);
    }

    k_pool<<<(N_NODES + POOL_CHUNK - 1) / POOL_CHUNK, 256, 0, stream>>>(outs[2], bnsc, batch, g);
    k_final<<<(N_GRAPHS * OUTC + 255) / 256, 256, 0, stream>>>(g, Wlin, blin, out);
}